// Round 1
// baseline (818.661 us; speedup 1.0000x reference)
//
#include <hip/hip_runtime.h>
#include <math.h>

// CNN_tcn, d-split version: B=256 samples, one block per sample (grid 256),
// 1024 threads = 2 threads per row a; thread (a,h) owns d in [32h, 32h+32).
// Doubles occupancy (2 -> 4 waves/SIMD) and halves each thread's serial
// global-load chain vs the 512-thread one-thread-per-row version.
// All cross-thread data (conv halos at the d=32 seam, t16a partials) moves
// through LDS; every global read-after-write is same-thread, so the in-place
// base2 -> base3 update stays race-free.
// Workspace: ONE [B][D][A] float4 buffer (128 MiB), same as before.

#define EPS_LN 1e-5f
typedef float4 f4;

__device__ __forceinline__ float gelu_f(float v) {
    return 0.5f * v * (1.0f + erff(v * 0.70710678118654752440f));
}

// y[o] = dilated conv taps: a = base[d-2], c = base[d], e = base[d+2]
// wd layout (4,4,1,3): [o][cin][k] flat o*12 + cin*3 + k
__device__ __forceinline__ void conv4(const f4 a, const f4 c, const f4 e,
                                      const float* __restrict__ wd, float y[4]) {
#pragma unroll
    for (int o = 0; o < 4; ++o) {
        const float* wv = wd + o * 12;
        y[o] = fmaf(a.x, wv[0], fmaf(c.x, wv[1], fmaf(e.x, wv[2],
               fmaf(a.y, wv[3], fmaf(c.y, wv[4], fmaf(e.y, wv[5],
               fmaf(a.z, wv[6], fmaf(c.z, wv[7], fmaf(e.z, wv[8],
               fmaf(a.w, wv[9], fmaf(c.w, wv[10], e.w * wv[11])))))))))));
    }
}

// block-wide reduce of (a,b2) over 1024 threads (16 waves)
__device__ __forceinline__ void block_red2(float& a, float& b2, float* red,
                                           float* bc, int tid) {
#pragma unroll
    for (int off = 32; off > 0; off >>= 1) {
        a  += __shfl_down(a,  off, 64);
        b2 += __shfl_down(b2, off, 64);
    }
    if ((tid & 63) == 0) { red[tid >> 6] = a; red[16 + (tid >> 6)] = b2; }
    __syncthreads();
    if (tid == 0) {
        float x = 0.f, y = 0.f;
#pragma unroll
        for (int i = 0; i < 16; ++i) { x += red[i]; y += red[16 + i]; }
        bc[0] = x; bc[1] = y;
    }
    __syncthreads();
    a = bc[0]; b2 = bc[1];
}

// normalize y (scale r, bias c = -m*r), pointwise wp -> gelu -> g[4];
// accumulate concat-LN stats (cs1,cs2) and the 16 t16a accumulators.
__device__ __forceinline__ void pw_accum(const float y[4], float r, float c,
    const float* __restrict__ wp, const float* __restrict__ cw, int cwo,
    const float* __restrict__ c2w, int d,
    float& cs1, float& cs2, float* t16a, float g[4]) {
    float yn[4];
#pragma unroll
    for (int o = 0; o < 4; ++o) yn[o] = fmaf(y[o], r, c);
#pragma unroll
    for (int o = 0; o < 4; ++o) {
        float zz = fmaf(yn[0], wp[o*4+0], fmaf(yn[1], wp[o*4+1],
                   fmaf(yn[2], wp[o*4+2], yn[3] * wp[o*4+3])));
        g[o] = gelu_f(zz);
    }
#pragma unroll
    for (int o = 0; o < 4; ++o) { cs1 += g[o]; cs2 = fmaf(g[o], g[o], cs2); }
    float u[4];
#pragma unroll
    for (int co = 0; co < 4; ++co)
        u[co] = fmaf(g[0], cw[co*12+cwo+0], fmaf(g[1], cw[co*12+cwo+1],
                fmaf(g[2], cw[co*12+cwo+2], g[3] * cw[co*12+cwo+3])));
#pragma unroll
    for (int o = 0; o < 16; ++o) {
        const float* p = c2w + o * 256 + d;
        t16a[o] = fmaf(u[0], p[0], fmaf(u[1], p[64],
                  fmaf(u[2], p[128], fmaf(u[3], p[192], t16a[o]))));
    }
}

__global__ __launch_bounds__(1024)
void tcn_fused(const float* __restrict__ sIn, const float* __restrict__ wIn,
               const float* __restrict__ w1d, const float* __restrict__ w1p,
               const float* __restrict__ w2d, const float* __restrict__ w2p,
               const float* __restrict__ w3d, const float* __restrict__ w3p,
               const float* __restrict__ cw,  const float* __restrict__ c2w,
               const float* __restrict__ c3w, float* __restrict__ out,
               f4* __restrict__ baseT) {
    const int b   = blockIdx.x;
    const int tid = threadIdx.x;
    const int a   = tid & 511;              // row
    const int h   = tid >> 9;               // d-half: 0 -> [0,32), 1 -> [32,64)
    const int Dlo = h << 5;

    __shared__ float red[32];
    __shared__ float bc[2];
    __shared__ float Klds[16];
    // halo slot [a][0] = base[30],[31] (written by h=0); [a][1] = base[32],[33] (h=1)
    __shared__ f4 haloA[512][2][2];          // base2 seam values
    __shared__ f4 haloB[512][2][2];          // base3 seam values
    __shared__ float t16p[512][17];          // h=1 partial t16a (stride 17: conflict-free)

    // K[o] = sum_{co,d} c2w[o,co,d] * (sum_{j<12} cw[co*12+j])
    if (tid < 16) {
        float k = 0.f;
        for (int co = 0; co < 4; ++co) {
            float csum = 0.f;
            for (int j = 0; j < 12; ++j) csum += cw[co * 12 + j];
            const float* p = c2w + tid * 256 + co * 64;
            float t = 0.f;
            for (int d = 0; d < 64; ++d) t += p[d];
            k = fmaf(csum, t, k);
        }
        Klds[tid] = k;
    }

    const f4* srow = (const f4*)sIn + ((size_t)b * 512 + a) * 64;  // s: [b][a][d] f4
    f4* brow = baseT + (size_t)b * (64 * 512) + a;                 // base: [b][d][a] f4
    const f4 z4 = make_float4(0.f, 0.f, 0.f, 0.f);
    const float NY = 4.f * 512.f * 64.f;                           // 131072

    auto ldS = [&](int d) -> f4 { return ((unsigned)d < 64u) ? srow[d] : z4; };
    auto ldB2 = [&](int d) -> f4 {                                 // base2 with LDS halos
        if (d >= Dlo && d < Dlo + 32) return brow[(size_t)d * 512];
        if (h) { if (d == 30) return haloA[a][0][0];
                 if (d == 31) return haloA[a][0][1]; }
        else   { if (d == 32) return haloA[a][1][0];
                 if (d == 33) return haloA[a][1][1]; }
        return z4;
    };
    auto ldB3 = [&](int d) -> f4 {                                 // base3 with LDS halos
        if (d >= Dlo && d < Dlo + 32) return brow[(size_t)d * 512];
        if (h) { if (d == 30) return haloB[a][0][0];
                 if (d == 31) return haloB[a][0][1]; }
        else   { if (d == 32) return haloB[a][1][0];
                 if (d == 33) return haloB[a][1][1]; }
        return z4;
    };

    // ---------- Phase A: stats of y1 = conv(s) ----------
    float s1 = 0.f, s2 = 0.f;
    {
        f4 wA = ldS(Dlo - 2), wB = ldS(Dlo - 1), wC = ldS(Dlo), wD = ldS(Dlo + 1), wE;
        for (int i = 0; i < 32; ++i) {
            const int d = Dlo + i;
            wE = ldS(d + 2);
            float y[4]; conv4(wA, wC, wE, w1d, y);
#pragma unroll
            for (int o = 0; o < 4; ++o) { s1 += y[o]; s2 = fmaf(y[o], y[o], s2); }
            wA = wB; wB = wC; wC = wD; wD = wE;
        }
    }
    block_red2(s1, s2, red, bc, tid);
    float m1 = s1 / NY;
    float r1 = rsqrtf(s2 / NY - m1 * m1 + EPS_LN);
    float c1n = -m1 * r1;

    float t16a[16];
#pragma unroll
    for (int o = 0; o < 16; ++o) t16a[o] = 0.f;
    float cs1 = 0.f, cs2 = 0.f;

    // ---------- Phase B: x1, store base2 = s + x1, export seam to LDS ----------
    {
        const int cap0 = h ? Dlo : Dlo + 30;   // h=1 exports its first two, h=0 its last two
        f4 capA0 = z4, capA1 = z4;
        f4 wA = ldS(Dlo - 2), wB = ldS(Dlo - 1), wC = ldS(Dlo), wD = ldS(Dlo + 1), wE;
        for (int i = 0; i < 32; ++i) {
            const int d = Dlo + i;
            wE = ldS(d + 2);
            float y[4]; conv4(wA, wC, wE, w1d, y);
            float g[4];
            pw_accum(y, r1, c1n, w1p, cw, 0, c2w, d, cs1, cs2, t16a, g);
            f4 nb;
            nb.x = wC.x + g[0]; nb.y = wC.y + g[1];
            nb.z = wC.z + g[2]; nb.w = wC.w + g[3];
            brow[(size_t)d * 512] = nb;
            if (d == cap0) capA0 = nb; else if (d == cap0 + 1) capA1 = nb;
            wA = wB; wB = wC; wC = wD; wD = wE;
        }
        haloA[a][h][0] = capA0; haloA[a][h][1] = capA1;
    }
    __syncthreads();                           // haloA visible; all base2 stored

    // ---------- Phase B2: stats of y2 = conv(base2) ----------
    float q1 = 0.f, q2 = 0.f;
    {
        f4 wA = ldB2(Dlo - 2), wB = ldB2(Dlo - 1), wC = ldB2(Dlo), wD = ldB2(Dlo + 1), wE;
        for (int i = 0; i < 32; ++i) {
            const int d = Dlo + i;
            wE = ldB2(d + 2);
            float y[4]; conv4(wA, wC, wE, w2d, y);
#pragma unroll
            for (int o = 0; o < 4; ++o) { q1 += y[o]; q2 = fmaf(y[o], y[o], q2); }
            wA = wB; wB = wC; wC = wD; wD = wE;
        }
    }
    block_red2(q1, q2, red, bc, tid);
    float m2s = q1 / NY;
    float r2s = rsqrtf(q2 / NY - m2s * m2s + EPS_LN);
    float c2n = -m2s * r2s;

    // ---------- Phase C: x2, base3 = base2 + x2 (in place), export seam ----------
    // In-place safety: own-range base2[d] is read (as vE) at iteration d-2, written
    // (as base3[d]) at iteration d; partner-range values only ever come from haloA.
    {
        const int cap0 = h ? Dlo : Dlo + 30;
        f4 capB0 = z4, capB1 = z4;
        f4 vA = ldB2(Dlo - 2), vB = ldB2(Dlo - 1), vC = ldB2(Dlo), vD = ldB2(Dlo + 1), vE;
        for (int i = 0; i < 32; ++i) {
            const int d = Dlo + i;
            vE = ldB2(d + 2);
            float y[4]; conv4(vA, vC, vE, w2d, y);
            float g[4];
            pw_accum(y, r2s, c2n, w2p, cw, 4, c2w, d, cs1, cs2, t16a, g);
            f4 nb;
            nb.x = vC.x + g[0]; nb.y = vC.y + g[1];
            nb.z = vC.z + g[2]; nb.w = vC.w + g[3];
            brow[(size_t)d * 512] = nb;
            if (d == cap0) capB0 = nb; else if (d == cap0 + 1) capB1 = nb;
            vA = vB; vB = vC; vC = vD; vD = vE;
        }
        haloB[a][h][0] = capB0; haloB[a][h][1] = capB1;
    }
    __syncthreads();                           // haloB visible; all base3 stored

    // ---------- Phase C2: stats of y3 = conv(base3) ----------
    float q31 = 0.f, q32 = 0.f;
    {
        f4 wA = ldB3(Dlo - 2), wB = ldB3(Dlo - 1), wC = ldB3(Dlo), wD = ldB3(Dlo + 1), wE;
        for (int i = 0; i < 32; ++i) {
            const int d = Dlo + i;
            wE = ldB3(d + 2);
            float y[4]; conv4(wA, wC, wE, w3d, y);
#pragma unroll
            for (int o = 0; o < 4; ++o) { q31 += y[o]; q32 = fmaf(y[o], y[o], q32); }
            wA = wB; wB = wC; wC = wD; wD = wE;
        }
    }
    block_red2(q31, q32, red, bc, tid);
    float m3s = q31 / NY;
    float r3s = rsqrtf(q32 / NY - m3s * m3s + EPS_LN);
    float c3n = -m3s * r3s;

    // ---------- Phase D: x3 ----------
    {
        f4 wA = ldB3(Dlo - 2), wB = ldB3(Dlo - 1), wC = ldB3(Dlo), wD = ldB3(Dlo + 1), wE;
        for (int i = 0; i < 32; ++i) {
            const int d = Dlo + i;
            wE = ldB3(d + 2);
            float y[4]; conv4(wA, wC, wE, w3d, y);
            float g[4];
            pw_accum(y, r3s, c3n, w3p, cw, 8, c2w, d, cs1, cs2, t16a, g);
            wA = wB; wB = wC; wC = wD; wD = wE;
        }
    }

    // ---------- combine t16a partials + concat LN stats over [12,A,D] ----------
    if (h == 1) {
#pragma unroll
        for (int o = 0; o < 16; ++o) t16p[a][o] = t16a[o];
    }
    block_red2(cs1, cs2, red, bc, tid);        // syncs also publish t16p
    const float NC = 12.f * 512.f * 64.f;      // 393216
    float mcat = cs1 / NC;
    float rcat = rsqrtf(cs2 / NC - mcat * mcat + EPS_LN);

    // t16 values for this row (h=0 threads own the tail); LN over [16, A]
    float tv[16];
    float p1 = 0.f, p2 = 0.f;
    if (h == 0) {
#pragma unroll
        for (int o = 0; o < 16; ++o) {
            float tot = t16a[o] + t16p[a][o];
            float v = rcat * (tot - mcat * Klds[o]);
            tv[o] = v; p1 += v; p2 = fmaf(v, v, p2);
        }
    }
    block_red2(p1, p2, red, bc, tid);
    const float N16 = 16.f * 512.f;            // 8192
    float m16 = p1 / N16;
    float r16 = rsqrtf(p2 / N16 - m16 * m16 + EPS_LN);

    // c3w over 17 channels (16 normalized + raw w), then LN over A
    float v = 0.f, f1 = 0.f, f2 = 0.f;
    if (h == 0) {
        v = wIn[(size_t)b * 512 + a] * c3w[16];
#pragma unroll
        for (int o = 0; o < 16; ++o) v = fmaf((tv[o] - m16) * r16, c3w[o], v);
        f1 = v; f2 = v * v;
    }
    block_red2(f1, f2, red, bc, tid);
    float mA = f1 / 512.f;
    float rA = rsqrtf(f2 / 512.f - mA * mA + EPS_LN);
    if (h == 0) out[(size_t)b * 512 + a] = (v - mA) * rA;
}

extern "C" void kernel_launch(void* const* d_in, const int* in_sizes, int n_in,
                              void* d_out, int out_size, void* d_ws, size_t ws_size,
                              hipStream_t stream) {
    const float* s   = (const float*)d_in[0];
    const float* w   = (const float*)d_in[1];
    const float* w1d = (const float*)d_in[2];
    const float* w1p = (const float*)d_in[3];
    const float* w2d = (const float*)d_in[4];
    const float* w2p = (const float*)d_in[5];
    const float* w3d = (const float*)d_in[6];
    const float* w3p = (const float*)d_in[7];
    const float* cw  = (const float*)d_in[8];
    const float* c2w = (const float*)d_in[9];
    const float* c3w = (const float*)d_in[10];
    tcn_fused<<<dim3(256), dim3(1024), 0, stream>>>(
        s, w, w1d, w1p, w2d, w2p, w3d, w3p, cw, c2w, c3w,
        (float*)d_out, (f4*)d_ws);
}